// Round 5
// baseline (146.666 us; speedup 1.0000x reference)
//
#include <hip/hip_runtime.h>
#include <math.h>

#define B 1024
#define O 256
#define D 1024
#define ALPHA 0.005f

#define K  2             // b rows per thread
#define NQ (D / 4)       // float4 steps over D
#define PF 4             // prefetch depth (rotating register buffers)

// Kernel 0: transpose c[O][D] -> ct[D/4][O] (float4 elements)
__global__ __launch_bounds__(256) void transpose_c(const float* __restrict__ c,
                                                   float4* __restrict__ ct)
{
    const int o  = threadIdx.x;         // 0..255
    const int d4 = blockIdx.x;          // 0..D/4-1
    const float* src = c + (size_t)o * D + d4 * 4;
    ct[(size_t)d4 * O + o] = make_float4(src[0], src[1], src[2], src[3]);
}

// Kernel 1 (fused): block = 256 threads = all o's for TWO b rows.
//  - c: per-lane coalesced from ct, explicit 4-deep rotating register prefetch
//  - x: wave-uniform addresses (blockIdx only) -> scalar-load candidates,
//       prefetched in the same rotation
//  - epilogue: alpha row-correction via shuffle reduce + 32B LDS
__global__ __launch_bounds__(256) void dist_fused(const float* __restrict__ x,
                                                  const float4* __restrict__ ct,
                                                  float* __restrict__ out)
{
    const int o  = threadIdx.x;
    const int b0 = blockIdx.x * K;

    const float4* cp  = ct + o;                               // step O per q
    const float4* xq0 = (const float4*)(x + (size_t)b0 * D);
    const float4* xq1 = (const float4*)(x + (size_t)(b0 + 1) * D);

    float s1a = 0.f, s2a = 0.f, s1b = 0.f, s2b = 0.f;

    float4 cb[PF], xa[PF], xb[PF];
    #pragma unroll
    for (int i = 0; i < PF; ++i) {
        cb[i] = cp[(size_t)i * O];
        xa[i] = xq0[i];
        xb[i] = xq1[i];
    }

    for (int q = 0; q < NQ; q += PF) {
        #pragma unroll
        for (int i = 0; i < PF; ++i) {
            const float4 cv = cb[i];
            const float4 x0 = xa[i];
            const float4 x1 = xb[i];
            // issue next loads (distance PF) before the compute
            const int nq = (q + i + PF < NQ) ? (q + i + PF) : (NQ - 1);
            cb[i] = cp[(size_t)nq * O];
            xa[i] = xq0[nq];
            xb[i] = xq1[nq];

            float d0 = x0.x - cv.x, d1 = x0.y - cv.y,
                  d2 = x0.z - cv.z, d3 = x0.w - cv.w;
            s1a += __builtin_fabsf(d0); s2a = __builtin_fmaf(d0, d0, s2a);
            s1a += __builtin_fabsf(d1); s2a = __builtin_fmaf(d1, d1, s2a);
            s1a += __builtin_fabsf(d2); s2a = __builtin_fmaf(d2, d2, s2a);
            s1a += __builtin_fabsf(d3); s2a = __builtin_fmaf(d3, d3, s2a);

            d0 = x1.x - cv.x; d1 = x1.y - cv.y;
            d2 = x1.z - cv.z; d3 = x1.w - cv.w;
            s1b += __builtin_fabsf(d0); s2b = __builtin_fmaf(d0, d0, s2b);
            s1b += __builtin_fabsf(d1); s2b = __builtin_fmaf(d1, d1, s2b);
            s1b += __builtin_fabsf(d2); s2b = __builtin_fmaf(d2, d2, s2b);
            s1b += __builtin_fabsf(d3); s2b = __builtin_fmaf(d3, d3, s2b);
        }
    }

    const float va = s1a + 0.5f * __builtin_sqrtf(s2a);
    const float vb = s1b + 0.5f * __builtin_sqrtf(s2b);

    float ta = va, tb = vb;
    #pragma unroll
    for (int off = 32; off >= 1; off >>= 1) {
        ta += __shfl_down(ta, off, 64);
        tb += __shfl_down(tb, off, 64);
    }

    __shared__ float ws[2][4];
    if ((o & 63) == 0) { ws[0][o >> 6] = ta; ws[1][o >> 6] = tb; }
    __syncthreads();
    const float Sa = ws[0][0] + ws[0][1] + ws[0][2] + ws[0][3];
    const float Sb = ws[1][0] + ws[1][1] + ws[1][2] + ws[1][3];

    out[(size_t)b0 * O + o]       = ALPHA * Sa - (1.0f + ALPHA) * va;
    out[(size_t)(b0 + 1) * O + o] = ALPHA * Sb - (1.0f + ALPHA) * vb;
}

extern "C" void kernel_launch(void* const* d_in, const int* in_sizes, int n_in,
                              void* d_out, int out_size, void* d_ws, size_t ws_size,
                              hipStream_t stream) {
    const float* x = (const float*)d_in[0];   // [B, D]
    const float* c = (const float*)d_in[1];   // [O, D]
    float* out = (float*)d_out;               // [B, O]

    float4* ct = (float4*)d_ws;               // [D/4, O] = 1 MB

    transpose_c<<<D / 4, O, 0, stream>>>(c, ct);
    dist_fused<<<B / K, 256, 0, stream>>>(x, ct, out);
}

// Round 6
// 93.131 us; speedup vs baseline: 1.5748x; 1.5748x over previous
//
#include <hip/hip_runtime.h>
#include <math.h>

#define B 1024
#define O 256
#define D 1024
#define ALPHA 0.005f

#define K   4            // b rows per thread
#define DS  8            // D splits (blockIdx.y)
#define DCH (D / DS)     // 128 d per block
#define NQ  (DCH / 4)    // 32 float4 steps

// Kernel 0: transpose c[O][D] -> ct[D/4][O] (float4 elements)
__global__ __launch_bounds__(256) void transpose_c(const float* __restrict__ c,
                                                   float4* __restrict__ ct)
{
    const int o  = threadIdx.x;         // 0..255
    const int d4 = blockIdx.x;          // 0..D/4-1
    const float* src = c + (size_t)o * D + d4 * 4;
    ct[(size_t)d4 * O + o] = make_float4(src[0], src[1], src[2], src[3]);
}

// Kernel 1: partial sums. Occupancy is the latency-hiding mechanism:
// 2048 blocks x 256 thr = 8 blocks/CU = 32 waves/CU (100%), VGPR capped 64.
// Per q-step per wave: 96 cy VALU vs ~500 cy load latency -> 8 waves/SIMD
// fully cover the stall with zero ILP required.
//  - c: per-lane coalesced from ct (1 float4 / thread / step)
//  - x: wave-uniform addresses (blockIdx only) -> scalar loads
__global__ __launch_bounds__(256, 8) void dist_part(const float* __restrict__ x,
                                                    const float4* __restrict__ ct,
                                                    float* __restrict__ s1p,
                                                    float* __restrict__ s2p)
{
    const int o  = threadIdx.x;               // centroid index
    const int b0 = blockIdx.x * K;            // first b row
    const int ds = blockIdx.y;                // d-slice
    const int d4 = ds * NQ;                   // base float4-index into ct rows

    const float4* cp = ct + (size_t)d4 * O + o;        // step O per q
    const float4* xp0 = (const float4*)(x + (size_t)(b0 + 0) * D) + d4;
    const float4* xp1 = (const float4*)(x + (size_t)(b0 + 1) * D) + d4;
    const float4* xp2 = (const float4*)(x + (size_t)(b0 + 2) * D) + d4;
    const float4* xp3 = (const float4*)(x + (size_t)(b0 + 3) * D) + d4;

    float s1[K], s2[K];
    #pragma unroll
    for (int i = 0; i < K; ++i) { s1[i] = 0.f; s2[i] = 0.f; }

    #pragma unroll 4
    for (int q = 0; q < NQ; ++q) {
        const float4 cv = cp[(size_t)q * O];
        const float4 xv0 = xp0[q];
        const float4 xv1 = xp1[q];
        const float4 xv2 = xp2[q];
        const float4 xv3 = xp3[q];

#define ACC(I, XV)                                                          \
        {                                                                   \
            const float d0 = XV.x - cv.x, d1 = XV.y - cv.y,                 \
                        d2 = XV.z - cv.z, d3 = XV.w - cv.w;                 \
            s1[I] += __builtin_fabsf(d0); s2[I] = __builtin_fmaf(d0, d0, s2[I]); \
            s1[I] += __builtin_fabsf(d1); s2[I] = __builtin_fmaf(d1, d1, s2[I]); \
            s1[I] += __builtin_fabsf(d2); s2[I] = __builtin_fmaf(d2, d2, s2[I]); \
            s1[I] += __builtin_fabsf(d3); s2[I] = __builtin_fmaf(d3, d3, s2[I]); \
        }
        ACC(0, xv0) ACC(1, xv1) ACC(2, xv2) ACC(3, xv3)
#undef ACC
    }

    #pragma unroll
    for (int i = 0; i < K; ++i) {
        const size_t idx = ((size_t)ds * B + (b0 + i)) * O + o;
        s1p[idx] = s1[i];
        s2p[idx] = s2[i];
    }
}

// Kernel 2: combine D-slices, sqrt + temperature + alpha row-correction.
__global__ __launch_bounds__(256) void combine_kernel(const float* __restrict__ s1p,
                                                      const float* __restrict__ s2p,
                                                      float* __restrict__ out)
{
    const int b = blockIdx.x;
    const int o = threadIdx.x;

    float a1 = 0.f, a2 = 0.f;
    #pragma unroll
    for (int ds = 0; ds < DS; ++ds) {
        const size_t idx = ((size_t)ds * B + b) * O + o;
        a1 += s1p[idx];
        a2 += s2p[idx];
    }
    const float v = a1 + 0.5f * __builtin_sqrtf(a2);

    float t = v;
    #pragma unroll
    for (int off = 32; off >= 1; off >>= 1)
        t += __shfl_down(t, off, 64);

    __shared__ float ws[4];
    if ((o & 63) == 0) ws[o >> 6] = t;
    __syncthreads();
    const float S = ws[0] + ws[1] + ws[2] + ws[3];

    out[(size_t)b * O + o] = ALPHA * S - (1.0f + ALPHA) * v;
}

extern "C" void kernel_launch(void* const* d_in, const int* in_sizes, int n_in,
                              void* d_out, int out_size, void* d_ws, size_t ws_size,
                              hipStream_t stream) {
    const float* x = (const float*)d_in[0];   // [B, D]
    const float* c = (const float*)d_in[1];   // [O, D]
    float* out = (float*)d_out;               // [B, O]

    float*  s1p = (float*)d_ws;                          // [DS, B, O] = 8 MB
    float*  s2p = s1p + (size_t)DS * B * O;              // [DS, B, O] = 8 MB
    float4* ct  = (float4*)(s2p + (size_t)DS * B * O);   // [D/4, O]   = 1 MB

    transpose_c<<<D / 4, O, 0, stream>>>(c, ct);

    dim3 grid(B / K, DS);                     // (256, 8) = 2048 blocks
    dist_part<<<grid, 256, 0, stream>>>(x, ct, s1p, s2p);
    combine_kernel<<<B, 256, 0, stream>>>(s1p, s2p, out);
}